// Round 14
// baseline (246.096 us; speedup 1.0000x reference)
//
#include <hip/hip_runtime.h>
#include <stdint.h>

#define NB 4
#define NS 2048
#define ND 1024
#define NH 16
#define NDK 64
#define NM (NB*NS)   // 8192 rows total

typedef __attribute__((ext_vector_type(8))) short short8;
typedef __attribute__((ext_vector_type(8))) unsigned short ushort8v;
typedef __attribute__((ext_vector_type(4))) float f32x4;
typedef __attribute__((ext_vector_type(16))) float f32x16;

typedef struct { uint32_t u[4]; } u32x4s;

__device__ __forceinline__ unsigned short f2bf(float f) {
  union { float f; uint32_t u; } v; v.f = f;
  uint32_t u = v.u;
  return (unsigned short)((u + 0x7FFFu + ((u >> 16) & 1u)) >> 16);
}

__device__ __forceinline__ uint32_t cvtpk(float lo, float hi) {
  uint32_t r;
  asm("v_cvt_pk_bf16_f32 %0, %1, %2" : "=v"(r) : "v"(lo), "v"(hi));
  return r;
}

__device__ __forceinline__ void gload16(const void* g, void* l) {
  __builtin_amdgcn_global_load_lds(
      (const __attribute__((address_space(1))) void*)g,
      (__attribute__((address_space(3))) void*)l, 16, 0, 0);
}

// T1: bijective XCD swizzle (requires nwg % 8 == 0)
__device__ __forceinline__ int xcd_swz(int flat, int nwg) {
  return (flat & 7) * (nwg >> 3) + (flat >> 3);
}

// ================== 256xBN deep-pipelined GEMM, fp32-fused staging ==================
// A: fp32 (A32=1, reg-staged+cvt) or bf16 (A32=0, gload_lds). B: same via B32.
// 4 phases/K-tile, early-issued staging, source-side XOR swizzle, raw barriers.
#define GPHASE(MH, NH, LA, LB)                                                 \
  {                                                                            \
    if (LA) {                                                                  \
      _Pragma("unroll") for (int mm = 0; mm < 4; ++mm)                         \
        _Pragma("unroll") for (int kk = 0; kk < 2; ++kk)                       \
          af[mm][kk] = *(const short8*)(Ab + (MH)*8192 + mm*2048 + rowb + aoff[kk]); \
    }                                                                          \
    if (LB) {                                                                  \
      _Pragma("unroll") for (int nn = 0; nn < NN; ++nn)                        \
        _Pragma("unroll") for (int kk = 0; kk < 2; ++kk)                       \
          bf[nn][kk] = *(const short8*)(Bb + (NH)*(NN*2048) + nn*2048 + rowb + aoff[kk]); \
    }                                                                          \
    __builtin_amdgcn_s_barrier();                                              \
    __builtin_amdgcn_s_setprio(1);                                             \
    _Pragma("unroll") for (int mm = 0; mm < 4; ++mm)                           \
      _Pragma("unroll") for (int nn = 0; nn < NN; ++nn)                        \
        _Pragma("unroll") for (int kk = 0; kk < 2; ++kk)                       \
          acc[(MH)*4+mm][(NH)*NN+nn] = __builtin_amdgcn_mfma_f32_16x16x32_bf16( \
              af[mm][kk], bf[nn][kk], acc[(MH)*4+mm][(NH)*NN+nn], 0, 0, 0);    \
    __builtin_amdgcn_s_setprio(0);                                             \
    __builtin_amdgcn_s_barrier();                                              \
  }

template<int OUT, int PRESCALE, int BN, int A32, int B32>
__device__ __forceinline__ void gemm256_core(
    const void* __restrict__ Ap,
    const void* __restrict__ Btp,
    void* __restrict__ Cout,
    unsigned short* lds, int m0, int n0)
{
  const int K = ND, N = ND;
  const int NN = BN / 128;
  const int NAL = 4;                 // A chunks per thread (BM=256)
  const int NBL = BN / 64;           // B chunks per thread
  const int ASZ = 16384, BSZ = BN * 64, SZ = ASZ + BSZ;
  const int tid = threadIdx.x;
  const int lane = tid & 63, wid = tid >> 6;
  const int l15 = lane & 15, lg = lane >> 4;
  const int wr = wid >> 2, wc = wid & 3;
  const float QSC = 0.125f * 1.44269504088896f;

  // staging geometry: chunk cidx = l*512+tid -> row r, slot ch; data = global
  // chunk ch^(r&7); LDS dest elem = cidx*8 (linear).
  size_t aofs[NAL], bofs[NBL];
#pragma unroll
  for (int l = 0; l < NAL; ++l) {
    int cidx = l*512 + tid;
    int r = cidx >> 3;
    int cs = ((cidx & 7) ^ (r & 7)) * 8;
    aofs[l] = (size_t)(m0 + r)*K + cs;
  }
#pragma unroll
  for (int l = 0; l < NBL; ++l) {
    int cidx = l*512 + tid;
    int r = cidx >> 3;
    int cs = ((cidx & 7) ^ (r & 7)) * 8;
    bofs[l] = (size_t)(n0 + r)*K + cs;
  }

  const int rowb = l15 * 128;
  int aoff[2];
  aoff[0] = ((lg)     ^ (l15 & 7)) * 16;
  aoff[1] = ((4 + lg) ^ (l15 & 7)) * 16;

  f32x4 acc[8][2*NN] = {};
  short8 af[4][2], bf[NN][2];

  f32x4 sa[NAL][2], sb[NBL][2];      // fp32 staged data (if A32/B32)

  // ---- prologue: stage K-tile 0 into buf 0 ----
#pragma unroll
  for (int l = 0; l < NAL; ++l) {
    if (A32) {
      const float* s = (const float*)Ap + aofs[l];
      sa[l][0] = *(const f32x4*)s; sa[l][1] = *(const f32x4*)(s + 4);
    } else
      gload16((const unsigned short*)Ap + aofs[l], lds + l*4096 + tid*8);
  }
#pragma unroll
  for (int l = 0; l < NBL; ++l) {
    if (B32) {
      const float* s = (const float*)Btp + bofs[l];
      sb[l][0] = *(const f32x4*)s; sb[l][1] = *(const f32x4*)(s + 4);
    } else
      gload16((const unsigned short*)Btp + bofs[l], lds + ASZ + l*4096 + tid*8);
  }
  if (A32) {
#pragma unroll
    for (int l = 0; l < NAL; ++l) {
      u32x4s h = { cvtpk(sa[l][0].x, sa[l][0].y), cvtpk(sa[l][0].z, sa[l][0].w),
                   cvtpk(sa[l][1].x, sa[l][1].y), cvtpk(sa[l][1].z, sa[l][1].w) };
      *(u32x4s*)(lds + l*4096 + tid*8) = h;
    }
  }
  if (B32) {
#pragma unroll
    for (int l = 0; l < NBL; ++l) {
      u32x4s h = { cvtpk(sb[l][0].x, sb[l][0].y), cvtpk(sb[l][0].z, sb[l][0].w),
                   cvtpk(sb[l][1].x, sb[l][1].y), cvtpk(sb[l][1].z, sb[l][1].w) };
      *(u32x4s*)(lds + ASZ + l*4096 + tid*8) = h;
    }
  }
  asm volatile("s_waitcnt vmcnt(0) lgkmcnt(0)" ::: "memory");
  __builtin_amdgcn_s_barrier();

  const int NT = K / 64;   // 16
  for (int t = 0; t < NT; ++t) {
    const int cur = t & 1;
    unsigned short* dst = lds + (cur^1)*SZ;
    // issue next tile's loads (regs for fp32, gload_lds for bf16)
    if (t + 1 < NT) {
      const int ko = (t+1)*64;
#pragma unroll
      for (int l = 0; l < NAL; ++l) {
        if (A32) {
          const float* s = (const float*)Ap + aofs[l] + ko;
          sa[l][0] = *(const f32x4*)s; sa[l][1] = *(const f32x4*)(s + 4);
        } else
          gload16((const unsigned short*)Ap + aofs[l] + ko, dst + l*4096 + tid*8);
      }
#pragma unroll
      for (int l = 0; l < NBL; ++l) {
        if (B32) {
          const float* s = (const float*)Btp + bofs[l] + ko;
          sb[l][0] = *(const f32x4*)s; sb[l][1] = *(const f32x4*)(s + 4);
        } else
          gload16((const unsigned short*)Btp + bofs[l] + ko, dst + ASZ + l*4096 + tid*8);
      }
    }
    const char* Ab = (const char*)(lds + cur*SZ) + wr*16384;
    const char* Bb = (const char*)(lds + cur*SZ + ASZ) + wc*(BN*32);

    GPHASE(0, 0, 1, 1)
    GPHASE(0, 1, 0, 1)
    GPHASE(1, 1, 1, 0)

    // write staged A (loads had ~3 phases to land; compiler inserts the wait)
    if (A32 && t + 1 < NT) {
#pragma unroll
      for (int l = 0; l < NAL; ++l) {
        u32x4s h = { cvtpk(sa[l][0].x, sa[l][0].y), cvtpk(sa[l][0].z, sa[l][0].w),
                     cvtpk(sa[l][1].x, sa[l][1].y), cvtpk(sa[l][1].z, sa[l][1].w) };
        *(u32x4s*)(dst + l*4096 + tid*8) = h;
      }
    }

    GPHASE(1, 0, 0, 1)

    if (B32 && t + 1 < NT) {
#pragma unroll
      for (int l = 0; l < NBL; ++l) {
        u32x4s h = { cvtpk(sb[l][0].x, sb[l][0].y), cvtpk(sb[l][0].z, sb[l][0].w),
                     cvtpk(sb[l][1].x, sb[l][1].y), cvtpk(sb[l][1].z, sb[l][1].w) };
        *(u32x4s*)(dst + ASZ + l*4096 + tid*8) = h;
      }
    }
    // drain LDS-DMA (if any) + own ds_writes, then block-wide publish
    asm volatile("s_waitcnt vmcnt(0) lgkmcnt(0)" ::: "memory");
    __builtin_amdgcn_s_barrier();
  }

  // epilogue: C/D layout col=lane&15, row=(lane>>4)*4+i
#pragma unroll
  for (int m = 0; m < 8; ++m)
#pragma unroll
    for (int n = 0; n < 2*NN; ++n)
#pragma unroll
      for (int i = 0; i < 4; ++i) {
        int row = m0 + wr*128 + m*16 + lg*4 + i;
        int col = n0 + wc*(BN/4) + n*16 + l15;
        float val = PRESCALE ? acc[m][n][i] * QSC : acc[m][n][i];
        if (OUT == 0)
          ((float*)Cout)[(size_t)row * N + col] = val;
        else if (OUT == 1)
          ((unsigned short*)Cout)[(size_t)row * N + col] = f2bf(val);
        else
          ((unsigned short*)Cout)[((size_t)((row >> 11)*1024 + col))*NS + (row & (NS-1))]
              = f2bf(val);
      }
}

// combined Q/K/V projection straight from fp32 inputs+weights (no convert pass).
// LDS 128KB -> 1 block/CU; (512,1) -> 256-VGPR cap (staged regs + acc fit).
__global__ __launch_bounds__(512, 1) void gemm_qkv(
    const float* __restrict__ Xq, const float* __restrict__ Wq, unsigned short* Qb,
    const float* __restrict__ Xk, const float* __restrict__ Wk, unsigned short* Kb,
    const float* __restrict__ Xv, const float* __restrict__ Wv, unsigned short* VbT)
{
  __shared__ unsigned short lds[65536];   // 128 KB
  int flat = (blockIdx.z * 32 + blockIdx.y) * 4 + blockIdx.x;
  int swz = xcd_swz(flat, 384);
  int z = swz >> 7, rem = swz & 127;
  int m0 = (rem >> 2) * 256, n0 = (rem & 3) * 256;
  if (z == 0)      gemm256_core<1,1,256,1,1>(Xq, Wq, Qb,  lds, m0, n0);
  else if (z == 1) gemm256_core<1,0,256,1,1>(Xk, Wk, Kb,  lds, m0, n0);
  else             gemm256_core<2,0,256,1,1>(Xv, Wv, VbT, lds, m0, n0);
}

// O-projection: A = bf16 O (gload_lds), B = fp32 Wo (reg-staged).
__global__ __launch_bounds__(512, 1) void gemm_o(
    const unsigned short* __restrict__ A, const float* __restrict__ Bt, float* C)
{
  __shared__ unsigned short lds[49152];   // 96 KB
  int flat = blockIdx.y * 8 + blockIdx.x;
  int swz = xcd_swz(flat, 256);
  gemm256_core<0,0,128,0,1>(A, Bt, C, lds, (swz >> 3) * 256, (swz & 7) * 128);
}

// ---------------- Flash attention (R9 structure — best measured, 94.4 us) ----------
// grid: (S/256, B*H) -> 512 blocks, 256 thr, 4 waves x 64 q (2 q-sets share
// K/V frag reads), KVBLK=64, LDS dbuf 32KB. Group-major conflict-free tiles;
// exact no-max softmax; in-register P via cvt_pk + permlane32_swap.
__global__ __launch_bounds__(256, 2) void flash_attn(
    const unsigned short* __restrict__ Qb,   // pre-scaled by 0.125*log2e
    const unsigned short* __restrict__ Kb,
    const unsigned short* __restrict__ VT,   // [B*H*64][2048] = V^T per head
    unsigned short* __restrict__ O)          // bf16 [8192][1024]
{
  __shared__ unsigned short Kt[2][64*64];    // [g=d-group][s-row][8 elems]
  __shared__ unsigned short Vt[2][64*64];    // [g=s-group][d-row][8 elems]
  const int tid = threadIdx.x, lane = tid & 63, wid = tid >> 6;
  const int l31 = lane & 31, hi = lane >> 5;
  int flat = blockIdx.y * 8 + blockIdx.x;
  int swz = xcd_swz(flat, 512);
  const int bh = swz >> 3, b = bh >> 4, h = bh & 15;
  const int q0 = (swz & 7) * 256 + wid * 64;

  const unsigned short* Kp[2]; const unsigned short* Vp[2]; int dofs[2];
#pragma unroll
  for (int p = 0; p < 2; ++p) {
    int slot = tid + p*256;
    int g = slot >> 6, r = slot & 63;
    Kp[p] = Kb + ((size_t)(b*NS + r))*ND + h*64 + g*8;
    Vp[p] = VT + ((size_t)(bh*64 + r))*NS + g*8;
    dofs[p] = slot * 8;
  }

  short8 qf[2][4];
#pragma unroll
  for (int qs = 0; qs < 2; ++qs)
#pragma unroll
    for (int ks = 0; ks < 4; ++ks)
      qf[qs][ks] = *(const short8*)(Qb + (size_t)(b*NS + q0 + qs*32 + l31)*ND + h*64 + ks*16 + hi*8);

  f32x16 oacc[2][2] = {};
  float lsum[2] = {0.f, 0.f};

#pragma unroll
  for (int p = 0; p < 2; ++p) {
    gload16(Kp[p], &Kt[0][dofs[p]]);
    gload16(Vp[p], &Vt[0][dofs[p]]);
  }
  __syncthreads();

  for (int t = 0; t < NS/64; ++t) {
    const int cur = t & 1;
    if (t + 1 < NS/64) {
#pragma unroll
      for (int p = 0; p < 2; ++p) {
        gload16(Kp[p] + (size_t)(t+1)*64*ND, &Kt[cur^1][dofs[p]]);
        gload16(Vp[p] + (t+1)*64,            &Vt[cur^1][dofs[p]]);
      }
    }
    const char* Kc = (const char*)Kt[cur];
    const char* Vc = (const char*)Vt[cur];

    short8 pa[2][2][2];
    float rs[2] = {0.f, 0.f};

#pragma unroll
    for (int n = 0; n < 2; ++n) {
      f32x16 st[2] = {};
      const int r = n*32 + l31;
      __builtin_amdgcn_s_setprio(1);
#pragma unroll
      for (int ks = 0; ks < 4; ++ks) {
        short8 kf = *(const short8*)(Kc + (((2*ks + hi) << 10) + r*16));
        st[0] = __builtin_amdgcn_mfma_f32_32x32x16_bf16(kf, qf[0][ks], st[0], 0, 0, 0);
        st[1] = __builtin_amdgcn_mfma_f32_32x32x16_bf16(kf, qf[1][ks], st[1], 0, 0, 0);
      }
      __builtin_amdgcn_s_setprio(0);
#pragma unroll
      for (int qs = 0; qs < 2; ++qs) {
        float lrs = 0.f;
#pragma unroll
        for (int e = 0; e < 16; ++e) {
          float p = __builtin_amdgcn_exp2f(st[qs][e]);
          st[qs][e] = p;
          lrs += p;
        }
        rs[qs] += lrs;
        uint32_t w[4][2];
#pragma unroll
        for (int e = 0; e < 4; ++e) {
          w[e][0] = cvtpk(st[qs][4*e+0], st[qs][4*e+1]);
          w[e][1] = cvtpk(st[qs][4*e+2], st[qs][4*e+3]);
        }
#pragma unroll
        for (int ksl = 0; ksl < 2; ++ksl) {
          uint32_t a0 = w[2*ksl][0], b0 = w[2*ksl+1][0];
          uint32_t a1 = w[2*ksl][1], b1 = w[2*ksl+1][1];
          asm("v_permlane32_swap_b32 %0, %1" : "+v"(a0), "+v"(b0));
          asm("v_permlane32_swap_b32 %0, %1" : "+v"(a1), "+v"(b1));
          union { uint32_t u[4]; short8 s; } f;
          f.u[0] = a0; f.u[1] = a1; f.u[2] = b0; f.u[3] = b1;
          pa[qs][n][ksl] = f.s;
        }
      }
    }
#pragma unroll
    for (int qs = 0; qs < 2; ++qs) {
      rs[qs] += __shfl_xor(rs[qs], 32);
      lsum[qs] += rs[qs];
    }

    __builtin_amdgcn_s_setprio(1);
#pragma unroll
    for (int d = 0; d < 2; ++d) {
      const int dr = d*32 + l31;
#pragma unroll
      for (int n = 0; n < 2; ++n)
#pragma unroll
        for (int ksl = 0; ksl < 2; ++ksl) {
          const int g = n*4 + ksl*2 + hi;
          short8 vf = *(const short8*)(Vc + ((g << 10) + dr*16));
          oacc[0][d] = __builtin_amdgcn_mfma_f32_32x32x16_bf16(pa[0][n][ksl], vf, oacc[0][d], 0, 0, 0);
          oacc[1][d] = __builtin_amdgcn_mfma_f32_32x32x16_bf16(pa[1][n][ksl], vf, oacc[1][d], 0, 0, 0);
        }
    }
    __builtin_amdgcn_s_setprio(0);
    __syncthreads();
  }

#pragma unroll
  for (int qs = 0; qs < 2; ++qs) {
    float linv[16];
#pragma unroll
    for (int r = 0; r < 16; ++r)
      linv[r] = 1.0f / __shfl(lsum[qs], (r & 3) + 8*(r >> 2) + 4*hi);
#pragma unroll
    for (int d = 0; d < 2; ++d)
#pragma unroll
      for (int r = 0; r < 16; ++r) {
        int qrow = q0 + qs*32 + (r & 3) + 8*(r >> 2) + 4*hi;
        O[(size_t)(b*NS + qrow)*ND + h*64 + d*32 + l31] = f2bf(oacc[qs][d][r] * linv[r]);
      }
  }
}

// ---------------- launch ----------------
extern "C" void kernel_launch(void* const* d_in, const int* in_sizes, int n_in,
                              void* d_out, int out_size, void* d_ws, size_t ws_size,
                              hipStream_t stream) {
  const float* q  = (const float*)d_in[0];
  const float* k  = (const float*)d_in[1];
  const float* v  = (const float*)d_in[2];
  const float* wq = (const float*)d_in[3];
  const float* wk = (const float*)d_in[4];
  const float* wv = (const float*)d_in[5];
  const float* wo = (const float*)d_in[6];

  unsigned short* Qb = (unsigned short*)d_ws;
  unsigned short* Kb = Qb + (size_t)NM*ND;
  unsigned short* Ob = Kb + (size_t)NM*ND;        // 48 MB total ws use
  unsigned short* VbT = (unsigned short*)d_out;   // scratch in d_out; rewritten by gemm_o

  gemm_qkv<<<dim3(4, 32, 3), 512, 0, stream>>>(q, wq, Qb, k, wk, Kb, v, wv, VbT);

  flash_attn<<<dim3(8, 64), 256, 0, stream>>>(Qb, Kb, VbT, Ob);

  gemm_o<<<dim3(8, 32), 512, 0, stream>>>(Ob, wo, (float*)d_out);
}

// Round 15
// 203.398 us; speedup vs baseline: 1.2099x; 1.2099x over previous
//
#include <hip/hip_runtime.h>
#include <stdint.h>

#define NB 4
#define NS 2048
#define ND 1024
#define NH 16
#define NDK 64
#define NM (NB*NS)   // 8192 rows total

typedef __attribute__((ext_vector_type(8))) short short8;
typedef __attribute__((ext_vector_type(8))) unsigned short ushort8v;
typedef __attribute__((ext_vector_type(4))) float f32x4;
typedef __attribute__((ext_vector_type(16))) float f32x16;

__device__ __forceinline__ unsigned short f2bf(float f) {
  union { float f; uint32_t u; } v; v.f = f;
  uint32_t u = v.u;
  return (unsigned short)((u + 0x7FFFu + ((u >> 16) & 1u)) >> 16);
}

__device__ __forceinline__ void gload16(const void* g, void* l) {
  __builtin_amdgcn_global_load_lds(
      (const __attribute__((address_space(1))) void*)g,
      (__attribute__((address_space(3))) void*)l, 16, 0, 0);
}

// T1: bijective XCD swizzle (requires nwg % 8 == 0)
__device__ __forceinline__ int xcd_swz(int flat, int nwg) {
  return (flat & 7) * (nwg >> 3) + (flat >> 3);
}

// ---------------- fused conversion fp32 -> bf16 (q,k,v + 4 weights) ----------------
__global__ void convert_all(
    const float* __restrict__ x0, const float* __restrict__ x1, const float* __restrict__ x2,
    const float* __restrict__ w0, const float* __restrict__ w1,
    const float* __restrict__ w2, const float* __restrict__ w3,
    unsigned short* __restrict__ ox0, unsigned short* __restrict__ ox1, unsigned short* __restrict__ ox2,
    unsigned short* __restrict__ ow0, unsigned short* __restrict__ ow1,
    unsigned short* __restrict__ ow2, unsigned short* __restrict__ ow3)
{
  const float* src;
  unsigned short* dst;
  size_t i;
  if (blockIdx.y < 3) {
    src = blockIdx.y == 0 ? x0 : (blockIdx.y == 1 ? x1 : x2);
    dst = blockIdx.y == 0 ? ox0 : (blockIdx.y == 1 ? ox1 : ox2);
    i = ((size_t)blockIdx.x * 256 + threadIdx.x) * 8;
  } else {
    if (blockIdx.x >= 2048) return;
    size_t e = ((size_t)blockIdx.x * 256 + threadIdx.x) * 8;
    int which = (int)(e >> 20);
    size_t off = e & ((1u << 20) - 1);
    const float* ws[4] = {w0, w1, w2, w3};
    unsigned short* wd[4] = {ow0, ow1, ow2, ow3};
    src = ws[which]; dst = wd[which]; i = off;
  }
  f32x4 a = *(const f32x4*)(src + i);
  f32x4 b = *(const f32x4*)(src + i + 4);
  ushort8v h;
  h[0]=f2bf(a.x); h[1]=f2bf(a.y); h[2]=f2bf(a.z); h[3]=f2bf(a.w);
  h[4]=f2bf(b.x); h[5]=f2bf(b.y); h[6]=f2bf(b.z); h[7]=f2bf(b.w);
  *(ushort8v*)(dst + i) = h;
}

// ================== 256xBN deep-pipelined GEMM (8 waves, BK=64) ==================
// Barrier-free tile interior: all phases read only buf[cur] (immutable this
// tile); staging writes only buf[cur^1]. One vmcnt(0)+s_barrier per K-tile.
// setprio(1) clusters around each 16-MFMA quadrant for wave arbitration.
#define GPHASE(MH, NH, LA, LB)                                                 \
  {                                                                            \
    if (LA) {                                                                  \
      _Pragma("unroll") for (int mm = 0; mm < 4; ++mm)                         \
        _Pragma("unroll") for (int kk = 0; kk < 2; ++kk)                       \
          af[mm][kk] = *(const short8*)(Ab + (MH)*8192 + mm*2048 + rowb + aoff[kk]); \
    }                                                                          \
    if (LB) {                                                                  \
      _Pragma("unroll") for (int nn = 0; nn < NN; ++nn)                        \
        _Pragma("unroll") for (int kk = 0; kk < 2; ++kk)                       \
          bf[nn][kk] = *(const short8*)(Bb + (NH)*(NN*2048) + nn*2048 + rowb + aoff[kk]); \
    }                                                                          \
    __builtin_amdgcn_s_setprio(1);                                             \
    _Pragma("unroll") for (int mm = 0; mm < 4; ++mm)                           \
      _Pragma("unroll") for (int nn = 0; nn < NN; ++nn)                        \
        _Pragma("unroll") for (int kk = 0; kk < 2; ++kk)                       \
          acc[(MH)*4+mm][(NH)*NN+nn] = __builtin_amdgcn_mfma_f32_16x16x32_bf16( \
              af[mm][kk], bf[nn][kk], acc[(MH)*4+mm][(NH)*NN+nn], 0, 0, 0);    \
    __builtin_amdgcn_s_setprio(0);                                             \
  }

template<int OUT, int PRESCALE, int BN>
__device__ __forceinline__ void gemm256_core(
    const unsigned short* __restrict__ A,
    const unsigned short* __restrict__ Bt,
    void* __restrict__ Cout,
    unsigned short* lds, int m0, int n0)
{
  const int K = ND, N = ND;
  const int NN = BN / 128;
  const int NBL = BN / 64;
  const int ASZ = 16384, BSZ = BN * 64, SZ = ASZ + BSZ;
  const int tid = threadIdx.x;
  const int lane = tid & 63, wid = tid >> 6;
  const int l15 = lane & 15, lg = lane >> 4;
  const int wr = wid >> 2, wc = wid & 3;
  const float QSC = 0.125f * 1.44269504088896f;

  const unsigned short* Asrc[4];
  const unsigned short* Bsrc[NBL];
#pragma unroll
  for (int l = 0; l < 4; ++l) {
    int cidx = l*512 + tid;
    int r = cidx >> 3;
    int cs = ((cidx & 7) ^ (r & 7)) * 8;
    Asrc[l] = A + (size_t)(m0 + r)*K + cs;
  }
#pragma unroll
  for (int l = 0; l < NBL; ++l) {
    int cidx = l*512 + tid;
    int r = cidx >> 3;
    int cs = ((cidx & 7) ^ (r & 7)) * 8;
    Bsrc[l] = Bt + (size_t)(n0 + r)*K + cs;
  }

  const int rowb = l15 * 128;
  int aoff[2];
  aoff[0] = ((lg)     ^ (l15 & 7)) * 16;
  aoff[1] = ((4 + lg) ^ (l15 & 7)) * 16;

  f32x4 acc[8][2*NN] = {};
  short8 af[4][2], bf[NN][2];

#pragma unroll
  for (int l = 0; l < 4; ++l) gload16(Asrc[l], lds + l*4096 + tid*8);
#pragma unroll
  for (int l = 0; l < NBL; ++l) gload16(Bsrc[l], lds + ASZ + l*4096 + tid*8);
  asm volatile("s_waitcnt vmcnt(0)" ::: "memory");
  __builtin_amdgcn_s_barrier();

  const int NT = K / 64;   // 16
  for (int t = 0; t < NT; ++t) {
    const int cur = t & 1;
    if (t + 1 < NT) {
      unsigned short* dst = lds + (cur^1)*SZ;
#pragma unroll
      for (int l = 0; l < 4; ++l) gload16(Asrc[l] + (t+1)*64, dst + l*4096 + tid*8);
#pragma unroll
      for (int l = 0; l < NBL; ++l) gload16(Bsrc[l] + (t+1)*64, dst + ASZ + l*4096 + tid*8);
    }
    const char* Ab = (const char*)(lds + cur*SZ) + wr*16384;
    const char* Bb = (const char*)(lds + cur*SZ + ASZ) + wc*(BN*32);

    GPHASE(0, 0, 1, 1)
    GPHASE(0, 1, 0, 1)
    GPHASE(1, 1, 1, 0)
    GPHASE(1, 0, 0, 1)

    // single sync point per K-tile: staging landed + all waves done reading
    asm volatile("s_waitcnt vmcnt(0)" ::: "memory");
    __builtin_amdgcn_s_barrier();
  }

#pragma unroll
  for (int m = 0; m < 8; ++m)
#pragma unroll
    for (int n = 0; n < 2*NN; ++n)
#pragma unroll
      for (int i = 0; i < 4; ++i) {
        int row = m0 + wr*128 + m*16 + lg*4 + i;
        int col = n0 + wc*(BN/4) + n*16 + l15;
        float val = PRESCALE ? acc[m][n][i] * QSC : acc[m][n][i];
        if (OUT == 0)
          ((float*)Cout)[(size_t)row * N + col] = val;
        else if (OUT == 1)
          ((unsigned short*)Cout)[(size_t)row * N + col] = f2bf(val);
        else
          ((unsigned short*)Cout)[((size_t)((row >> 11)*1024 + col))*NS + (row & (NS-1))]
              = f2bf(val);
      }
}

// LDS 128KB -> 1 block/CU regardless; (512,1) lifts the VGPR cap to 256 so
// acc[8][4]+frags (~190 regs) no longer spills (R10/R14: 2nd arg = blocks/CU).
__global__ __launch_bounds__(512, 1) void gemm_qkv(
    const unsigned short* __restrict__ Xq, const unsigned short* __restrict__ Wq, unsigned short* Qb,
    const unsigned short* __restrict__ Xk, const unsigned short* __restrict__ Wk, unsigned short* Kb,
    const unsigned short* __restrict__ Xv, const unsigned short* __restrict__ Wv, unsigned short* VbT)
{
  __shared__ unsigned short lds[65536];   // 128 KB
  int flat = (blockIdx.z * 32 + blockIdx.y) * 4 + blockIdx.x;
  int swz = xcd_swz(flat, 384);
  int z = swz >> 7, rem = swz & 127;
  int m0 = (rem >> 2) * 256, n0 = (rem & 3) * 256;
  if (z == 0)      gemm256_core<1,1,256>(Xq, Wq, Qb,  lds, m0, n0);
  else if (z == 1) gemm256_core<1,0,256>(Xk, Wk, Kb,  lds, m0, n0);
  else             gemm256_core<2,0,256>(Xv, Wv, VbT, lds, m0, n0);
}

__global__ __launch_bounds__(512, 1) void gemm_o(
    const unsigned short* __restrict__ A, const unsigned short* __restrict__ Bt, float* C)
{
  __shared__ unsigned short lds[49152];   // 96 KB
  int flat = blockIdx.y * 8 + blockIdx.x;
  int swz = xcd_swz(flat, 256);
  gemm256_core<0,0,128>(A, Bt, C, lds, (swz >> 3) * 256, (swz & 7) * 128);
}

// ---------------- Flash attention (R9 structure — best measured, 94.4 us) ----------
// grid: (S/256, B*H) -> 512 blocks, 256 thr, 4 waves x 64 q (2 q-sets share
// K/V frag reads), KVBLK=64, LDS dbuf 32KB. Group-major conflict-free tiles;
// exact no-max softmax; in-register P via cvt_pk + permlane32_swap.
__global__ __launch_bounds__(256, 2) void flash_attn(
    const unsigned short* __restrict__ Qb,   // pre-scaled by 0.125*log2e
    const unsigned short* __restrict__ Kb,
    const unsigned short* __restrict__ VT,   // [B*H*64][2048] = V^T per head
    unsigned short* __restrict__ O)          // bf16 [8192][1024]
{
  __shared__ unsigned short Kt[2][64*64];    // [g=d-group][s-row][8 elems]
  __shared__ unsigned short Vt[2][64*64];    // [g=s-group][d-row][8 elems]
  const int tid = threadIdx.x, lane = tid & 63, wid = tid >> 6;
  const int l31 = lane & 31, hi = lane >> 5;
  int flat = blockIdx.y * 8 + blockIdx.x;
  int swz = xcd_swz(flat, 512);
  const int bh = swz >> 3, b = bh >> 4, h = bh & 15;
  const int q0 = (swz & 7) * 256 + wid * 64;

  const unsigned short* Kp[2]; const unsigned short* Vp[2]; int dofs[2];
#pragma unroll
  for (int p = 0; p < 2; ++p) {
    int slot = tid + p*256;
    int g = slot >> 6, r = slot & 63;
    Kp[p] = Kb + ((size_t)(b*NS + r))*ND + h*64 + g*8;
    Vp[p] = VT + ((size_t)(bh*64 + r))*NS + g*8;
    dofs[p] = slot * 8;
  }

  short8 qf[2][4];
#pragma unroll
  for (int qs = 0; qs < 2; ++qs)
#pragma unroll
    for (int ks = 0; ks < 4; ++ks)
      qf[qs][ks] = *(const short8*)(Qb + (size_t)(b*NS + q0 + qs*32 + l31)*ND + h*64 + ks*16 + hi*8);

  f32x16 oacc[2][2] = {};
  float lsum[2] = {0.f, 0.f};

#pragma unroll
  for (int p = 0; p < 2; ++p) {
    gload16(Kp[p], &Kt[0][dofs[p]]);
    gload16(Vp[p], &Vt[0][dofs[p]]);
  }
  __syncthreads();

  for (int t = 0; t < NS/64; ++t) {
    const int cur = t & 1;
    if (t + 1 < NS/64) {
#pragma unroll
      for (int p = 0; p < 2; ++p) {
        gload16(Kp[p] + (size_t)(t+1)*64*ND, &Kt[cur^1][dofs[p]]);
        gload16(Vp[p] + (t+1)*64,            &Vt[cur^1][dofs[p]]);
      }
    }
    const char* Kc = (const char*)Kt[cur];
    const char* Vc = (const char*)Vt[cur];

    short8 pa[2][2][2];
    float rs[2] = {0.f, 0.f};

#pragma unroll
    for (int n = 0; n < 2; ++n) {
      f32x16 st[2] = {};
      const int r = n*32 + l31;
      __builtin_amdgcn_s_setprio(1);
#pragma unroll
      for (int ks = 0; ks < 4; ++ks) {
        short8 kf = *(const short8*)(Kc + (((2*ks + hi) << 10) + r*16));
        st[0] = __builtin_amdgcn_mfma_f32_32x32x16_bf16(kf, qf[0][ks], st[0], 0, 0, 0);
        st[1] = __builtin_amdgcn_mfma_f32_32x32x16_bf16(kf, qf[1][ks], st[1], 0, 0, 0);
      }
      __builtin_amdgcn_s_setprio(0);
#pragma unroll
      for (int qs = 0; qs < 2; ++qs) {
        float lrs = 0.f;
#pragma unroll
        for (int e = 0; e < 16; ++e) {
          float p = __builtin_amdgcn_exp2f(st[qs][e]);
          st[qs][e] = p;
          lrs += p;
        }
        rs[qs] += lrs;
        uint32_t w[4][2];
#pragma unroll
        for (int e = 0; e < 4; ++e) {
          asm("v_cvt_pk_bf16_f32 %0, %1, %2"
              : "=v"(w[e][0]) : "v"(st[qs][4*e+0]), "v"(st[qs][4*e+1]));
          asm("v_cvt_pk_bf16_f32 %0, %1, %2"
              : "=v"(w[e][1]) : "v"(st[qs][4*e+2]), "v"(st[qs][4*e+3]));
        }
#pragma unroll
        for (int ksl = 0; ksl < 2; ++ksl) {
          uint32_t a0 = w[2*ksl][0], b0 = w[2*ksl+1][0];
          uint32_t a1 = w[2*ksl][1], b1 = w[2*ksl+1][1];
          asm("v_permlane32_swap_b32 %0, %1" : "+v"(a0), "+v"(b0));
          asm("v_permlane32_swap_b32 %0, %1" : "+v"(a1), "+v"(b1));
          union { uint32_t u[4]; short8 s; } f;
          f.u[0] = a0; f.u[1] = a1; f.u[2] = b0; f.u[3] = b1;
          pa[qs][n][ksl] = f.s;
        }
      }
    }
#pragma unroll
    for (int qs = 0; qs < 2; ++qs) {
      rs[qs] += __shfl_xor(rs[qs], 32);
      lsum[qs] += rs[qs];
    }

    __builtin_amdgcn_s_setprio(1);
#pragma unroll
    for (int d = 0; d < 2; ++d) {
      const int dr = d*32 + l31;
#pragma unroll
      for (int n = 0; n < 2; ++n)
#pragma unroll
        for (int ksl = 0; ksl < 2; ++ksl) {
          const int g = n*4 + ksl*2 + hi;
          short8 vf = *(const short8*)(Vc + ((g << 10) + dr*16));
          oacc[0][d] = __builtin_amdgcn_mfma_f32_32x32x16_bf16(pa[0][n][ksl], vf, oacc[0][d], 0, 0, 0);
          oacc[1][d] = __builtin_amdgcn_mfma_f32_32x32x16_bf16(pa[1][n][ksl], vf, oacc[1][d], 0, 0, 0);
        }
    }
    __builtin_amdgcn_s_setprio(0);
    __syncthreads();
  }

#pragma unroll
  for (int qs = 0; qs < 2; ++qs) {
    float linv[16];
#pragma unroll
    for (int r = 0; r < 16; ++r)
      linv[r] = 1.0f / __shfl(lsum[qs], (r & 3) + 8*(r >> 2) + 4*hi);
#pragma unroll
    for (int d = 0; d < 2; ++d)
#pragma unroll
      for (int r = 0; r < 16; ++r) {
        int qrow = q0 + qs*32 + (r & 3) + 8*(r >> 2) + 4*hi;
        O[(size_t)(b*NS + qrow)*ND + h*64 + d*32 + l31] = f2bf(oacc[qs][d][r] * linv[r]);
      }
  }
}

// ---------------- launch ----------------
extern "C" void kernel_launch(void* const* d_in, const int* in_sizes, int n_in,
                              void* d_out, int out_size, void* d_ws, size_t ws_size,
                              hipStream_t stream) {
  const float* q  = (const float*)d_in[0];
  const float* k  = (const float*)d_in[1];
  const float* v  = (const float*)d_in[2];
  const float* wq = (const float*)d_in[3];
  const float* wk = (const float*)d_in[4];
  const float* wv = (const float*)d_in[5];
  const float* wo = (const float*)d_in[6];

  unsigned short* Wq = (unsigned short*)d_ws;
  unsigned short* Wk = Wq + (size_t)ND*ND;
  unsigned short* Wv = Wk + (size_t)ND*ND;
  unsigned short* Wo = Wv + (size_t)ND*ND;
  unsigned short* Xq = Wo + (size_t)ND*ND;
  unsigned short* Xk = Xq + (size_t)NM*ND;
  unsigned short* Xv = Xk + (size_t)NM*ND;
  unsigned short* Qb = Xv + (size_t)NM*ND;
  unsigned short* Kb = Qb + (size_t)NM*ND;
  unsigned short* VbT = (unsigned short*)d_out;   // scratch in d_out; rewritten by gemm_o
  unsigned short* Ob  = Xq;                       // alias: Xq dead after qkv launch

  convert_all<<<dim3(NM*ND/(256*8), 4), 256, 0, stream>>>(
      q, k, v, wq, wk, wv, wo, Xq, Xk, Xv, Wq, Wk, Wv, Wo);

  gemm_qkv<<<dim3(4, 32, 3), 512, 0, stream>>>(Xq, Wq, Qb, Xk, Wk, Kb, Xv, Wv, VbT);

  flash_attn<<<dim3(8, 64), 256, 0, stream>>>(Qb, Kb, VbT, Ob);

  gemm_o<<<dim3(8, 32), 512, 0, stream>>>(Ob, Wo, (float*)d_out);
}

// Round 16
// 200.413 us; speedup vs baseline: 1.2279x; 1.0149x over previous
//
#include <hip/hip_runtime.h>
#include <stdint.h>

#define NB 4
#define NS 2048
#define ND 1024
#define NH 16
#define NDK 64
#define NM (NB*NS)   // 8192 rows total

typedef __attribute__((ext_vector_type(8))) short short8;
typedef __attribute__((ext_vector_type(8))) unsigned short ushort8v;
typedef __attribute__((ext_vector_type(4))) float f32x4;
typedef __attribute__((ext_vector_type(16))) float f32x16;

__device__ __forceinline__ unsigned short f2bf(float f) {
  union { float f; uint32_t u; } v; v.f = f;
  uint32_t u = v.u;
  return (unsigned short)((u + 0x7FFFu + ((u >> 16) & 1u)) >> 16);
}

__device__ __forceinline__ void gload16(const void* g, void* l) {
  __builtin_amdgcn_global_load_lds(
      (const __attribute__((address_space(1))) void*)g,
      (__attribute__((address_space(3))) void*)l, 16, 0, 0);
}

// T1: bijective XCD swizzle (requires nwg % 8 == 0)
__device__ __forceinline__ int xcd_swz(int flat, int nwg) {
  return (flat & 7) * (nwg >> 3) + (flat >> 3);
}

// ---------------- fused conversion fp32 -> bf16 (q,k,v + 4 weights) ----------------
__global__ void convert_all(
    const float* __restrict__ x0, const float* __restrict__ x1, const float* __restrict__ x2,
    const float* __restrict__ w0, const float* __restrict__ w1,
    const float* __restrict__ w2, const float* __restrict__ w3,
    unsigned short* __restrict__ ox0, unsigned short* __restrict__ ox1, unsigned short* __restrict__ ox2,
    unsigned short* __restrict__ ow0, unsigned short* __restrict__ ow1,
    unsigned short* __restrict__ ow2, unsigned short* __restrict__ ow3)
{
  const float* src;
  unsigned short* dst;
  size_t i;
  if (blockIdx.y < 3) {
    src = blockIdx.y == 0 ? x0 : (blockIdx.y == 1 ? x1 : x2);
    dst = blockIdx.y == 0 ? ox0 : (blockIdx.y == 1 ? ox1 : ox2);
    i = ((size_t)blockIdx.x * 256 + threadIdx.x) * 8;
  } else {
    if (blockIdx.x >= 2048) return;
    size_t e = ((size_t)blockIdx.x * 256 + threadIdx.x) * 8;
    int which = (int)(e >> 20);
    size_t off = e & ((1u << 20) - 1);
    const float* ws[4] = {w0, w1, w2, w3};
    unsigned short* wd[4] = {ow0, ow1, ow2, ow3};
    src = ws[which]; dst = wd[which]; i = off;
  }
  f32x4 a = *(const f32x4*)(src + i);
  f32x4 b = *(const f32x4*)(src + i + 4);
  ushort8v h;
  h[0]=f2bf(a.x); h[1]=f2bf(a.y); h[2]=f2bf(a.z); h[3]=f2bf(a.w);
  h[4]=f2bf(b.x); h[5]=f2bf(b.y); h[6]=f2bf(b.z); h[7]=f2bf(b.w);
  *(ushort8v*)(dst + i) = h;
}

// ============ 256xBN GEMM, BK=32, 3-buffer rotation, counted vmcnt (T4) ============
// Per K-tile t (buf c=t%3): issue tile t+2's staging into buf (c+2)%3 (read
// last by tile t-1, published by the t-1 end barrier) -> at tile end wait
// vmcnt(NL) (t+1's loads landed; t+2's stay in flight) + one s_barrier. No
// drain-0 in steady state; every load has ~2 tiles to cover HBM/L2 latency.
// 32 MFMA/tile all hit DISTINCT accumulators (no intra-tile chains).
// LDS rows are 64B with chunk-swizzle slot = ch ^ ((r>>1)&3): both the
// linear-dest DMA write and the frag ds_read_b128 are <=2-way (free, m136).
template<int OUT, int PRESCALE, int BN>
__device__ __forceinline__ void gemm_bk32_core(
    const unsigned short* __restrict__ A,
    const unsigned short* __restrict__ Bt,
    void* __restrict__ Cout,
    unsigned short* lds, int m0, int n0)
{
  const int K = ND, N = ND;
  const int NBF = BN / 64;           // B frags per wave (4 or 2)
  const int NBL = BN / 128;          // B staging loads per thread (2 or 1)
  const int NL  = 2 + NBL;           // loads per tile per thread
  const int ASZ = 8192, BSZ = BN*32, SZ = ASZ + BSZ;   // elems
  const int NT = K / 32;             // 32 K-tiles
  const int tid = threadIdx.x;
  const int lane = tid & 63, wid = tid >> 6;
  const int l15 = lane & 15, lg = lane >> 4;
  const int wr = wid >> 2, wc = wid & 3;   // 2M x 4N waves; per-wave out 128x(BN/4)
  const float QSC = 0.125f * 1.44269504088896f;

  // staging: A chunk cidx = l*512+tid in [0,1024): row r=cidx>>2, slot cidx&3
  // holds global chunk (cidx&3)^((r>>1)&3); LDS dest = cidx*8 (linear).
  const unsigned short* Asrc[2];
  const unsigned short* Bsrc[2];
  int dofA[2], dofB[2];
#pragma unroll
  for (int l = 0; l < 2; ++l) {
    int cidx = l*512 + tid;
    int r = cidx >> 2;
    int ch = (cidx & 3) ^ ((r >> 1) & 3);
    Asrc[l] = A + (size_t)(m0 + r)*K + ch*8;
    dofA[l] = cidx * 8;
  }
#pragma unroll
  for (int l = 0; l < NBL; ++l) {
    int cidx = l*512 + tid;
    int r = cidx >> 2;
    int ch = (cidx & 3) ^ ((r >> 1) & 3);
    Bsrc[l] = Bt + (size_t)(n0 + r)*K + ch*8;
    dofB[l] = cidx * 8;
  }

  f32x4 acc[8][NBF] = {};

#define STAGE32(t, buf)                                                        \
  {                                                                            \
    unsigned short* d_ = lds + (buf)*SZ;                                       \
    _Pragma("unroll") for (int l = 0; l < 2; ++l)                              \
      gload16(Asrc[l] + (t)*32, d_ + dofA[l]);                                 \
    _Pragma("unroll") for (int l = 0; l < NBL; ++l)                            \
      gload16(Bsrc[l] + (t)*32, d_ + ASZ + dofB[l]);                           \
  }

  // prologue: tiles 0,1 into bufs 0,1; wait tile 0 (tile 1 stays in flight)
  STAGE32(0, 0)
  STAGE32(1, 1)
  if (NBL == 2) asm volatile("s_waitcnt vmcnt(4)" ::: "memory");
  else          asm volatile("s_waitcnt vmcnt(3)" ::: "memory");
  __builtin_amdgcn_s_barrier();

  int b0 = 0;
  for (int t = 0; t < NT; ++t) {
    if (t + 2 < NT) {
      int nb = b0 + 2; if (nb >= 3) nb -= 3;
      STAGE32(t + 2, nb)
    }
    const unsigned short* Abase = lds + b0*SZ;
    const unsigned short* Bbase = lds + b0*SZ + ASZ;

    short8 bfr[NBF];
#pragma unroll
    for (int nn = 0; nn < NBF; ++nn) {
      int row = wc*(BN/4) + nn*16 + l15;
      bfr[nn] = *(const short8*)(Bbase + row*32 + (lg ^ ((row >> 1) & 3))*8);
    }
#pragma unroll
    for (int mh = 0; mh < 2; ++mh) {
      short8 af[4];
#pragma unroll
      for (int mm = 0; mm < 4; ++mm) {
        int row = wr*128 + mh*64 + mm*16 + l15;
        af[mm] = *(const short8*)(Abase + row*32 + (lg ^ ((row >> 1) & 3))*8);
      }
      __builtin_amdgcn_s_setprio(1);
#pragma unroll
      for (int mm = 0; mm < 4; ++mm)
#pragma unroll
        for (int nn = 0; nn < NBF; ++nn)
          acc[mh*4+mm][nn] = __builtin_amdgcn_mfma_f32_16x16x32_bf16(
              af[mm], bfr[nn], acc[mh*4+mm][nn], 0, 0, 0);
      __builtin_amdgcn_s_setprio(0);
    }

    // boundary: t+1's loads must be visible; t+2's stay in flight (counted)
    if (t + 2 < NT) {
      if (NBL == 2) asm volatile("s_waitcnt vmcnt(4)" ::: "memory");
      else          asm volatile("s_waitcnt vmcnt(3)" ::: "memory");
      __builtin_amdgcn_s_barrier();
    } else if (t + 1 < NT) {
      asm volatile("s_waitcnt vmcnt(0)" ::: "memory");
      __builtin_amdgcn_s_barrier();
    }
    b0 = (b0 + 1 == 3) ? 0 : b0 + 1;
  }
#undef STAGE32

  // epilogue: C/D layout col=lane&15, row=(lane>>4)*4+i
#pragma unroll
  for (int m = 0; m < 8; ++m)
#pragma unroll
    for (int n = 0; n < NBF; ++n)
#pragma unroll
      for (int i = 0; i < 4; ++i) {
        int row = m0 + wr*128 + m*16 + lg*4 + i;
        int col = n0 + wc*(BN/4) + n*16 + l15;
        float val = PRESCALE ? acc[m][n][i] * QSC : acc[m][n][i];
        if (OUT == 0)
          ((float*)Cout)[(size_t)row * N + col] = val;
        else if (OUT == 1)
          ((unsigned short*)Cout)[(size_t)row * N + col] = f2bf(val);
        else
          ((unsigned short*)Cout)[((size_t)((row >> 11)*1024 + col))*NS + (row & (NS-1))]
              = f2bf(val);
      }
}

// qkv: BN=256 -> LDS 3 x 32KB = 96KB, 1 block/CU; (512,1) -> 256-VGPR cap.
__global__ __launch_bounds__(512, 1) void gemm_qkv(
    const unsigned short* __restrict__ Xq, const unsigned short* __restrict__ Wq, unsigned short* Qb,
    const unsigned short* __restrict__ Xk, const unsigned short* __restrict__ Wk, unsigned short* Kb,
    const unsigned short* __restrict__ Xv, const unsigned short* __restrict__ Wv, unsigned short* VbT)
{
  __shared__ unsigned short lds[3*16384];   // 96 KB
  int flat = (blockIdx.z * 32 + blockIdx.y) * 4 + blockIdx.x;
  int swz = xcd_swz(flat, 384);
  int z = swz >> 7, rem = swz & 127;
  int m0 = (rem >> 2) * 256, n0 = (rem & 3) * 256;
  if (z == 0)      gemm_bk32_core<1,1,256>(Xq, Wq, Qb,  lds, m0, n0);
  else if (z == 1) gemm_bk32_core<1,0,256>(Xk, Wk, Kb,  lds, m0, n0);
  else             gemm_bk32_core<2,0,256>(Xv, Wv, VbT, lds, m0, n0);
}

// o: BN=128 -> LDS 3 x 24KB = 72KB; 256 blocks = 1/CU.
__global__ __launch_bounds__(512, 1) void gemm_o(
    const unsigned short* __restrict__ A, const unsigned short* __restrict__ Bt, float* C)
{
  __shared__ unsigned short lds[3*12288];   // 72 KB
  int flat = blockIdx.y * 8 + blockIdx.x;
  int swz = xcd_swz(flat, 256);
  gemm_bk32_core<0,0,128>(A, Bt, C, lds, (swz >> 3) * 256, (swz & 7) * 128);
}

// ---------------- Flash attention (R9/R15 structure — best measured, 94 us) --------
__global__ __launch_bounds__(256, 2) void flash_attn(
    const unsigned short* __restrict__ Qb,   // pre-scaled by 0.125*log2e
    const unsigned short* __restrict__ Kb,
    const unsigned short* __restrict__ VT,   // [B*H*64][2048] = V^T per head
    unsigned short* __restrict__ O)          // bf16 [8192][1024]
{
  __shared__ unsigned short Kt[2][64*64];    // [g=d-group][s-row][8 elems]
  __shared__ unsigned short Vt[2][64*64];    // [g=s-group][d-row][8 elems]
  const int tid = threadIdx.x, lane = tid & 63, wid = tid >> 6;
  const int l31 = lane & 31, hi = lane >> 5;
  int flat = blockIdx.y * 8 + blockIdx.x;
  int swz = xcd_swz(flat, 512);
  const int bh = swz >> 3, b = bh >> 4, h = bh & 15;
  const int q0 = (swz & 7) * 256 + wid * 64;

  const unsigned short* Kp[2]; const unsigned short* Vp[2]; int dofs[2];
#pragma unroll
  for (int p = 0; p < 2; ++p) {
    int slot = tid + p*256;
    int g = slot >> 6, r = slot & 63;
    Kp[p] = Kb + ((size_t)(b*NS + r))*ND + h*64 + g*8;
    Vp[p] = VT + ((size_t)(bh*64 + r))*NS + g*8;
    dofs[p] = slot * 8;
  }

  short8 qf[2][4];
#pragma unroll
  for (int qs = 0; qs < 2; ++qs)
#pragma unroll
    for (int ks = 0; ks < 4; ++ks)
      qf[qs][ks] = *(const short8*)(Qb + (size_t)(b*NS + q0 + qs*32 + l31)*ND + h*64 + ks*16 + hi*8);

  f32x16 oacc[2][2] = {};
  float lsum[2] = {0.f, 0.f};

#pragma unroll
  for (int p = 0; p < 2; ++p) {
    gload16(Kp[p], &Kt[0][dofs[p]]);
    gload16(Vp[p], &Vt[0][dofs[p]]);
  }
  __syncthreads();

  for (int t = 0; t < NS/64; ++t) {
    const int cur = t & 1;
    if (t + 1 < NS/64) {
#pragma unroll
      for (int p = 0; p < 2; ++p) {
        gload16(Kp[p] + (size_t)(t+1)*64*ND, &Kt[cur^1][dofs[p]]);
        gload16(Vp[p] + (t+1)*64,            &Vt[cur^1][dofs[p]]);
      }
    }
    const char* Kc = (const char*)Kt[cur];
    const char* Vc = (const char*)Vt[cur];

    short8 pa[2][2][2];
    float rs[2] = {0.f, 0.f};

#pragma unroll
    for (int n = 0; n < 2; ++n) {
      f32x16 st[2] = {};
      const int r = n*32 + l31;
      __builtin_amdgcn_s_setprio(1);
#pragma unroll
      for (int ks = 0; ks < 4; ++ks) {
        short8 kf = *(const short8*)(Kc + (((2*ks + hi) << 10) + r*16));
        st[0] = __builtin_amdgcn_mfma_f32_32x32x16_bf16(kf, qf[0][ks], st[0], 0, 0, 0);
        st[1] = __builtin_amdgcn_mfma_f32_32x32x16_bf16(kf, qf[1][ks], st[1], 0, 0, 0);
      }
      __builtin_amdgcn_s_setprio(0);
#pragma unroll
      for (int qs = 0; qs < 2; ++qs) {
        float lrs = 0.f;
#pragma unroll
        for (int e = 0; e < 16; ++e) {
          float p = __builtin_amdgcn_exp2f(st[qs][e]);
          st[qs][e] = p;
          lrs += p;
        }
        rs[qs] += lrs;
        uint32_t w[4][2];
#pragma unroll
        for (int e = 0; e < 4; ++e) {
          asm("v_cvt_pk_bf16_f32 %0, %1, %2"
              : "=v"(w[e][0]) : "v"(st[qs][4*e+0]), "v"(st[qs][4*e+1]));
          asm("v_cvt_pk_bf16_f32 %0, %1, %2"
              : "=v"(w[e][1]) : "v"(st[qs][4*e+2]), "v"(st[qs][4*e+3]));
        }
#pragma unroll
        for (int ksl = 0; ksl < 2; ++ksl) {
          uint32_t a0 = w[2*ksl][0], b0 = w[2*ksl+1][0];
          uint32_t a1 = w[2*ksl][1], b1 = w[2*ksl+1][1];
          asm("v_permlane32_swap_b32 %0, %1" : "+v"(a0), "+v"(b0));
          asm("v_permlane32_swap_b32 %0, %1" : "+v"(a1), "+v"(b1));
          union { uint32_t u[4]; short8 s; } f;
          f.u[0] = a0; f.u[1] = a1; f.u[2] = b0; f.u[3] = b1;
          pa[qs][n][ksl] = f.s;
        }
      }
    }
#pragma unroll
    for (int qs = 0; qs < 2; ++qs) {
      rs[qs] += __shfl_xor(rs[qs], 32);
      lsum[qs] += rs[qs];
    }

    __builtin_amdgcn_s_setprio(1);
#pragma unroll
    for (int d = 0; d < 2; ++d) {
      const int dr = d*32 + l31;
#pragma unroll
      for (int n = 0; n < 2; ++n)
#pragma unroll
        for (int ksl = 0; ksl < 2; ++ksl) {
          const int g = n*4 + ksl*2 + hi;
          short8 vf = *(const short8*)(Vc + ((g << 10) + dr*16));
          oacc[0][d] = __builtin_amdgcn_mfma_f32_32x32x16_bf16(pa[0][n][ksl], vf, oacc[0][d], 0, 0, 0);
          oacc[1][d] = __builtin_amdgcn_mfma_f32_32x32x16_bf16(pa[1][n][ksl], vf, oacc[1][d], 0, 0, 0);
        }
    }
    __builtin_amdgcn_s_setprio(0);
    __syncthreads();
  }

#pragma unroll
  for (int qs = 0; qs < 2; ++qs) {
    float linv[16];
#pragma unroll
    for (int r = 0; r < 16; ++r)
      linv[r] = 1.0f / __shfl(lsum[qs], (r & 3) + 8*(r >> 2) + 4*hi);
#pragma unroll
    for (int d = 0; d < 2; ++d)
#pragma unroll
      for (int r = 0; r < 16; ++r) {
        int qrow = q0 + qs*32 + (r & 3) + 8*(r >> 2) + 4*hi;
        O[(size_t)(b*NS + qrow)*ND + h*64 + d*32 + l31] = f2bf(oacc[qs][d][r] * linv[r]);
      }
  }
}

// ---------------- launch ----------------
extern "C" void kernel_launch(void* const* d_in, const int* in_sizes, int n_in,
                              void* d_out, int out_size, void* d_ws, size_t ws_size,
                              hipStream_t stream) {
  const float* q  = (const float*)d_in[0];
  const float* k  = (const float*)d_in[1];
  const float* v  = (const float*)d_in[2];
  const float* wq = (const float*)d_in[3];
  const float* wk = (const float*)d_in[4];
  const float* wv = (const float*)d_in[5];
  const float* wo = (const float*)d_in[6];

  unsigned short* Wq = (unsigned short*)d_ws;
  unsigned short* Wk = Wq + (size_t)ND*ND;
  unsigned short* Wv = Wk + (size_t)ND*ND;
  unsigned short* Wo = Wv + (size_t)ND*ND;
  unsigned short* Xq = Wo + (size_t)ND*ND;
  unsigned short* Xk = Xq + (size_t)NM*ND;
  unsigned short* Xv = Xk + (size_t)NM*ND;
  unsigned short* Qb = Xv + (size_t)NM*ND;
  unsigned short* Kb = Qb + (size_t)NM*ND;
  unsigned short* VbT = (unsigned short*)d_out;   // scratch in d_out; rewritten by gemm_o
  unsigned short* Ob  = Xq;                       // alias: Xq dead after qkv launch

  convert_all<<<dim3(NM*ND/(256*8), 4), 256, 0, stream>>>(
      q, k, v, wq, wk, wv, wo, Xq, Xk, Xv, Wq, Wk, Wv, Wo);

  gemm_qkv<<<dim3(4, 32, 3), 512, 0, stream>>>(Xq, Wq, Qb, Xk, Wk, Kb, Xv, Wv, VbT);

  flash_attn<<<dim3(8, 64), 256, 0, stream>>>(Qb, Kb, VbT, Ob);

  gemm_o<<<dim3(8, 32), 512, 0, stream>>>(Ob, Wo, (float*)d_out);
}